// Round 13
// baseline (361.347 us; speedup 1.0000x reference)
//
#include <hip/hip_runtime.h>

typedef __attribute__((ext_vector_type(8))) short bf16x8;
typedef __attribute__((ext_vector_type(8))) unsigned short u16x8;
typedef __attribute__((ext_vector_type(4))) float f32x4;

#define MFMA16(a, b, c) __builtin_amdgcn_mfma_f32_16x16x32_bf16((a), (b), (c), 0, 0, 0)

__device__ __forceinline__ unsigned short f2bf(float f) {
  union { float f; unsigned u; } x; x.f = f;
  unsigned r = x.u + 0x7FFFu + ((x.u >> 16) & 1u);
  return (unsigned short)(r >> 16);
}
__device__ __forceinline__ float bf2f(unsigned short b) {
  union { unsigned u; float f; } x; x.u = ((unsigned)b) << 16;
  return x.f;
}

__device__ __forceinline__ void gld_lds16(const void* g, void* l) {
  __builtin_amdgcn_global_load_lds(
      (const __attribute__((address_space(1))) unsigned int*)g,
      (__attribute__((address_space(3))) unsigned int*)l, 16, 0, 0);
}

// -------- fused fp32 -> bf16 bulk convert for x, qkv_w, proj_w --------------
__global__ __launch_bounds__(256) void cvt3_kernel(const float* __restrict__ s0,
                                                   unsigned short* __restrict__ d0, int n0,
                                                   const float* __restrict__ s1,
                                                   unsigned short* __restrict__ d1, int n1,
                                                   const float* __restrict__ s2,
                                                   unsigned short* __restrict__ d2, int n2) {
  int i = blockIdx.x * 256 + threadIdx.x;
  const int stride = gridDim.x * 256;
  const int tot = n0 + n1 + n2;
  for (; i < tot; i += stride) {
    const float* s;
    unsigned short* d;
    int j = i;
    if (j < n0) { s = s0; d = d0; }
    else if (j < n0 + n1) { j -= n0; s = s1; d = d1; }
    else { j -= n0 + n1; s = s2; d = d2; }
    float4 f0 = ((const float4*)s)[2 * j];
    float4 f1 = ((const float4*)s)[2 * j + 1];
    u16x8 v;
    v[0] = f2bf(f0.x); v[1] = f2bf(f0.y); v[2] = f2bf(f0.z); v[3] = f2bf(f0.w);
    v[4] = f2bf(f1.x); v[5] = f2bf(f1.y); v[6] = f2bf(f1.z); v[7] = f2bf(f1.w);
    ((u16x8*)d)[j] = v;
  }
}

// ------- GEMM1: qkv, m97 A-staging + B-OPERAND IN REGISTERS (experiment) ----
// Bs LDS dropped; B-fragments are global->VGPR loads from L2-resident Wb.
// No barrier dependency on B loads -> compiler can hoist next-iter B loads
// across __syncthreads for natural cross-iteration overlap. Operand values
// and accumulation order bit-identical to R2 -> absmax must stay 9.765625e-4.
__global__ __launch_bounds__(256) void qkv_gemm(const unsigned short* __restrict__ X,
                                                const unsigned short* __restrict__ W,
                                                unsigned short* __restrict__ Qo,
                                                unsigned short* __restrict__ Ko,
                                                unsigned short* __restrict__ Vo) {
  __shared__ unsigned short As[128][64];
  const int tid = threadIdx.x;
  const int lane = tid & 63, wave = tid >> 6;
  const int lrow = lane & 15, lgrp = lane >> 4;
  const int wr = wave >> 1, wc = wave & 1;
  const int m0 = blockIdx.x * 128, n0 = blockIdx.y * 128;

  f32x4 acc[4][4];
#pragma unroll
  for (int i = 0; i < 4; i++)
#pragma unroll
    for (int j = 0; j < 4; j++) acc[i][j] = (f32x4){0.f, 0.f, 0.f, 0.f};

  const int rbase = wave * 32;
  const int srow = rbase + (lane >> 3);
  const int scol = (lane & 7) * 8;
  // B fragment base: row = n0 + wc*64 + f*16 + lrow, col = k0 + kk*32 + lgrp*8
  const unsigned short* wb = W + (size_t)(n0 + wc * 64 + lrow) * 768 + lgrp * 8;

#pragma unroll 2
  for (int k0 = 0; k0 < 768; k0 += 64) {
    const unsigned short* ga = X + (size_t)(m0 + srow) * 768 + k0 + scol;
#pragma unroll
    for (int i = 0; i < 4; i++)
      gld_lds16(ga + (size_t)i * 8 * 768, &As[rbase + i * 8][0]);
    __syncthreads();
#pragma unroll
    for (int kk = 0; kk < 2; kk++) {
      bf16x8 a[4], b[4];
#pragma unroll
      for (int f = 0; f < 4; f++)
        b[f] = *(const bf16x8*)(wb + (size_t)f * 16 * 768 + k0 + kk * 32);
#pragma unroll
      for (int f = 0; f < 4; f++)
        a[f] = *(const bf16x8*)(&As[wr * 64 + f * 16 + lrow][kk * 32 + lgrp * 8]);
#pragma unroll
      for (int i = 0; i < 4; i++)
#pragma unroll
        for (int j = 0; j < 4; j++) acc[i][j] = MFMA16(a[i], b[j], acc[i][j]);
    }
    __syncthreads();
  }

#pragma unroll
  for (int fj = 0; fj < 4; fj++) {
    const int jb = n0 + wc * 64 + fj * 16;
    const int s = jb / 768;
    const int hh = (jb % 768) >> 6;
    const int dd = (jb & 63) + lrow;
    unsigned short* dst = (s == 0) ? Qo : (s == 1) ? Ko : Vo;
#pragma unroll
    for (int fi = 0; fi < 4; fi++) {
#pragma unroll
      for (int r = 0; r < 4; r++) {
        int m = m0 + wr * 64 + fi * 16 + lgrp * 4 + r;
        int bb = m / 197;
        int nn = m - bb * 197;
        dst[(size_t)((bb * 12 + hh) * 197 + nn) * 64 + dd] = f2bf(acc[fi][fj][r]);
      }
    }
  }
}

// ---------------- GEMM3 (proven R2 structure, frozen) -----------------------
__global__ __launch_bounds__(256) void proj_gemm(const unsigned short* __restrict__ A,
                                                 const unsigned short* __restrict__ W,
                                                 const float* __restrict__ bias,
                                                 float* __restrict__ out) {
  __shared__ unsigned short As[128][64];
  __shared__ unsigned short Bs[128][64];
  const int tid = threadIdx.x;
  const int lane = tid & 63, wave = tid >> 6;
  const int lrow = lane & 15, lgrp = lane >> 4;
  const int wr = wave >> 1, wc = wave & 1;
  const int m0 = blockIdx.x * 128, n0 = blockIdx.y * 128;

  f32x4 acc[4][4];
#pragma unroll
  for (int i = 0; i < 4; i++)
#pragma unroll
    for (int j = 0; j < 4; j++) acc[i][j] = (f32x4){0.f, 0.f, 0.f, 0.f};

  const int rbase = wave * 32;
  const int srow = rbase + (lane >> 3);
  const int scol = (lane & 7) * 8;

  for (int k0 = 0; k0 < 768; k0 += 64) {
    const unsigned short* ga = A + (size_t)(m0 + srow) * 768 + k0 + scol;
    const unsigned short* gb = W + (size_t)(n0 + srow) * 768 + k0 + scol;
#pragma unroll
    for (int i = 0; i < 4; i++) {
      gld_lds16(ga + (size_t)i * 8 * 768, &As[rbase + i * 8][0]);
      gld_lds16(gb + (size_t)i * 8 * 768, &Bs[rbase + i * 8][0]);
    }
    __syncthreads();
#pragma unroll
    for (int kk = 0; kk < 2; kk++) {
      bf16x8 a[4], b[4];
#pragma unroll
      for (int f = 0; f < 4; f++) {
        a[f] = *(const bf16x8*)(&As[wr * 64 + f * 16 + lrow][kk * 32 + lgrp * 8]);
        b[f] = *(const bf16x8*)(&Bs[wc * 64 + f * 16 + lrow][kk * 32 + lgrp * 8]);
      }
#pragma unroll
      for (int i = 0; i < 4; i++)
#pragma unroll
        for (int j = 0; j < 4; j++) acc[i][j] = MFMA16(a[i], b[j], acc[i][j]);
    }
    __syncthreads();
  }

#pragma unroll
  for (int fj = 0; fj < 4; fj++) {
    const int j = n0 + wc * 64 + fj * 16 + lrow;
    const float bj = bias[j];
#pragma unroll
    for (int fi = 0; fi < 4; fi++) {
#pragma unroll
      for (int r = 0; r < 4; r++) {
        int m = m0 + wr * 64 + fi * 16 + lgrp * 4 + r;
        out[(size_t)m * 768 + j] = acc[fi][fj][r] + bj;
      }
    }
  }
}

// ===== Attention v6 (frozen from R12) =======================================
__global__ __launch_bounds__(512, 4) void attn_kernel(const unsigned short* __restrict__ Q,
                                                      const unsigned short* __restrict__ K,
                                                      const unsigned short* __restrict__ V,
                                                      const float* __restrict__ piq,
                                                      const float* __restrict__ pik,
                                                      unsigned short* __restrict__ Oa) {
  __shared__ __align__(16) unsigned char smem[81536];
  unsigned short* Ks = (unsigned short*)smem;               // [208][64] swz
  unsigned short* Vt = (unsigned short*)(smem + 26624);     // [64][216]
  unsigned short* Ps = (unsigned short*)(smem + 54272);     // [8][16][40]
  unsigned short* Vlin = (unsigned short*)(smem + 54272);   // [200][64] alias
  float* k2c = (float*)(smem + 79872);                      // [208]
  float* piqs = k2c + 208;                                  // [208]

  const int tid = threadIdx.x;
  const int lane = tid & 63, wave = tid >> 6;
  const int lrow = lane & 15, lgrp = lane >> 4;
  const int bh = blockIdx.x;
  const int h = bh % 12;
  const int b = bh / 12;
  const size_t kvbase = (size_t)bh * 197 * 64;
  const float c1 = -0.09016844005556021f;  // -0.0625 * log2(e)

  float my_pik = 0.f, my_piq = 0.f;
  if (tid < 197) { my_pik = pik[h * 197 + tid]; my_piq = piq[h * 197 + tid]; }
  const int t0 = wave, t1 = wave + 8;
  const int rq0 = min(t0 * 16 + lrow, 196);
  const int rq1 = (t1 < 13) ? min(t1 * 16 + lrow, 196) : rq0;
  const size_t qb0 = kvbase + (size_t)rq0 * 64 + lgrp * 8;
  const size_t qb1 = kvbase + (size_t)rq1 * 64 + lgrp * 8;
  const bf16x8 aqA0 = *(const bf16x8*)(Q + qb0);
  const bf16x8 aqA1 = *(const bf16x8*)(Q + qb0 + 32);
  const bf16x8 aqB0 = *(const bf16x8*)(Q + qb1);
  const bf16x8 aqB1 = *(const bf16x8*)(Q + qb1 + 32);

  {
    const int rl = lane >> 3;
    const int csw = ((lane & 7) ^ rl) * 8;
    const int cl = (lane & 7) * 8;
    for (int i = wave; i < 26; i += 8)
      gld_lds16(K + kvbase + (size_t)(i * 8 + rl) * 64 + csw, Ks + i * 512);
    for (int i = wave; i < 25; i += 8)
      gld_lds16(V + kvbase + (size_t)(i * 8 + rl) * 64 + cl, Vlin + i * 512);
  }
  __syncthreads();

  for (int c = tid; c < 1600; c += 512) {
    const int row = c >> 3, d0 = (c & 7) * 8;
    u16x8 v = *(const u16x8*)(Vlin + row * 64 + d0);
#pragma unroll
    for (int e = 0; e < 8; e++) Vt[(d0 + e) * 216 + row] = (unsigned short)v[e];
  }
  {
    const int i1 = tid + 512;
    Vt[(tid >> 4) * 216 + 200 + (tid & 15)] = 0;
    Vt[(i1 >> 4) * 216 + 200 + (i1 & 15)] = 0;
  }
  if (tid < 208) {
    const int n = tid;
    if (n < 197) {
      float k2 = 0.f;
#pragma unroll
      for (int c = 0; c < 8; c++) {
        u16x8 v = *(const u16x8*)(Ks + n * 64 + ((c ^ (n & 7)) << 3));
#pragma unroll
        for (int e = 0; e < 8; e++) { float f = bf2f((unsigned short)v[e]); k2 += f * f; }
      }
      const float pk = fminf(fabsf(my_pik), 1.f);
      k2c[n] = c1 * k2 + log2f(pk);
      piqs[n] = fminf(fabsf(my_piq), 1.f);
    } else {
      k2c[n] = -__builtin_inff();
      piqs[n] = 0.f;
    }
  }
  __syncthreads();

  unsigned short* Pw = Ps + wave * 640;  // [16][40]

#define ATTN_TILE(TT, AQ0, AQ1)                                               \
  {                                                                           \
    const int n0_ = (TT) * 16;                                                \
    float q2p = 0.f;                                                          \
    _Pragma("unroll") for (int e = 0; e < 8; e++) {                           \
      float f0 = bf2f((unsigned short)((u16x8)(AQ0))[e]); q2p += f0 * f0;     \
      float f1 = bf2f((unsigned short)((u16x8)(AQ1))[e]); q2p += f1 * f1;     \
    }                                                                         \
    q2p += __shfl_xor(q2p, 16);                                               \
    q2p += __shfl_xor(q2p, 32);                                               \
    float q2r[4];                                                             \
    _Pragma("unroll") for (int r = 0; r < 4; r++)                             \
        q2r[r] = __shfl(q2p, lgrp * 4 + r);                                   \
    float rs[4] = {0.f, 0.f, 0.f, 0.f};                                       \
    f32x4 o[4];                                                               \
    _Pragma("unroll") for (int dt = 0; dt < 4; dt++)                          \
        o[dt] = (f32x4){0.f, 0.f, 0.f, 0.f};                                  \
    for (int ks = 0; ks < 7; ks++) {                                          \
      _Pragma("unroll") for (int half = 0; half < 2; half++) {                \
        const int jt = ks * 2 + half;                                         \
        if (jt < 13) {                                                        \
          f32x4 sacc = (f32x4){0.f, 0.f, 0.f, 0.f};                           \
          const int rk = jt * 16 + lrow;                                      \
          bf16x8 bk0 = *(const bf16x8*)(Ks + rk * 64 +                        \
                                        (((0 + lgrp) ^ (rk & 7)) << 3));      \
          bf16x8 bk1 = *(const bf16x8*)(Ks + rk * 64 +                        \
                                        (((4 + lgrp) ^ (rk & 7)) << 3));      \
          __builtin_amdgcn_s_setprio(1);                                      \
          sacc = MFMA16((AQ0), bk0, sacc);                                    \
          sacc = MFMA16((AQ1), bk1, sacc);                                    \
          __builtin_amdgcn_s_setprio(0);                                      \
          const int j = jt * 16 + lrow;                                       \
          const float k2cj = k2c[j];                                          \
          _Pragma("unroll") for (int r = 0; r < 4; r++) {                     \
            float t1v = fmaf(-2.f, sacc[r], q2r[r]);                          \
            float p = exp2f(fmaf(c1, t1v, k2cj));                             \
            rs[r] += p;                                                       \
            Pw[(lgrp * 4 + r) * 40 + half * 16 + lrow] = f2bf(p);             \
          }                                                                   \
        } else {                                                              \
          _Pragma("unroll") for (int r = 0; r < 4; r++)                       \
              Pw[(lgrp * 4 + r) * 40 + 16 + lrow] = 0;                        \
        }                                                                     \
      }                                                                       \
      bf16x8 ap = *(const bf16x8*)(Pw + lrow * 40 + lgrp * 8);                \
      const int jcol = min(ks * 32 + lgrp * 8, 208);                          \
      __builtin_amdgcn_s_setprio(1);                                          \
      _Pragma("unroll") for (int dt = 0; dt < 4; dt++) {                      \
        bf16x8 bv = *(const bf16x8*)(Vt + (dt * 16 + lrow) * 216 + jcol);     \
        o[dt] = MFMA16(ap, bv, o[dt]);                                        \
      }                                                                       \
      __builtin_amdgcn_s_setprio(0);                                          \
    }                                                                         \
    _Pragma("unroll") for (int r = 0; r < 4; r++) {                           \
      float v = rs[r];                                                        \
      v += __shfl_xor(v, 1);                                                  \
      v += __shfl_xor(v, 2);                                                  \
      v += __shfl_xor(v, 4);                                                  \
      v += __shfl_xor(v, 8);                                                  \
      rs[r] = v;                                                              \
    }                                                                         \
    float scale[4];                                                           \
    _Pragma("unroll") for (int r = 0; r < 4; r++) {                           \
      float pq = piqs[n0_ + lgrp * 4 + r];                                    \
      scale[r] = pq / (pq * rs[r] + 1e-6f);                                   \
    }                                                                         \
    _Pragma("unroll") for (int r = 0; r < 4; r++) {                           \
      const int n = n0_ + lgrp * 4 + r;                                       \
      if (n < 197) {                                                          \
        const size_t ob = ((size_t)(b * 197 + n)) * 768 + h * 64;             \
        _Pragma("unroll") for (int dt = 0; dt < 4; dt++)                      \
            Oa[ob + dt * 16 + lrow] = f2bf(o[dt][r] * scale[r]);              \
      }                                                                       \
    }                                                                         \
  }

  ATTN_TILE(t0, aqA0, aqA1);
  if (t1 < 13) ATTN_TILE(t1, aqB0, aqB1);
#undef ATTN_TILE
}

extern "C" void kernel_launch(void* const* d_in, const int* in_sizes, int n_in,
                              void* d_out, int out_size, void* d_ws, size_t ws_size,
                              hipStream_t stream) {
  const float* x = (const float*)d_in[0];
  const float* qkv_w = (const float*)d_in[1];
  const float* proj_w = (const float*)d_in[2];
  const float* proj_b = (const float*)d_in[3];
  const float* pi_q = (const float*)d_in[4];
  const float* pi_k = (const float*)d_in[5];
  float* out = (float*)d_out;

  unsigned short* ws = (unsigned short*)d_ws;
  const size_t S = (size_t)1536 * 197 * 64;  // 19,365,888 elems per tensor
  unsigned short* Q = ws;
  unsigned short* K = ws + S;
  unsigned short* V = ws + 2 * S;
  unsigned short* Xb = ws + 3 * S;   // aliased: Oa reuses this region after qkv
  unsigned short* Oa = Xb;
  unsigned short* Wb = ws + 4 * S;                 // 2304*768 bf16
  unsigned short* Pb = Wb + (size_t)2304 * 768;    // 768*768 bf16

  dim3 blk(256, 1, 1);
  dim3 blk512(512, 1, 1);
  cvt3_kernel<<<dim3(2048, 1, 1), blk, 0, stream>>>(x, Xb, 2420736,
                                                    qkv_w, Wb, 221184,
                                                    proj_w, Pb, 73728);
  qkv_gemm<<<dim3(197, 18, 1), blk, 0, stream>>>(Xb, Wb, Q, K, V);
  attn_kernel<<<dim3(1536, 1, 1), blk512, 0, stream>>>(Q, K, V, pi_q, pi_k, Oa);
  proj_gemm<<<dim3(197, 6, 1), blk, 0, stream>>>(Oa, Pb, proj_b, out);
}

// Round 14
// 294.991 us; speedup vs baseline: 1.2249x; 1.2249x over previous
//
#include <hip/hip_runtime.h>

typedef __attribute__((ext_vector_type(8))) short bf16x8;
typedef __attribute__((ext_vector_type(8))) unsigned short u16x8;
typedef __attribute__((ext_vector_type(4))) float f32x4;

#define MFMA16(a, b, c) __builtin_amdgcn_mfma_f32_16x16x32_bf16((a), (b), (c), 0, 0, 0)

__device__ __forceinline__ unsigned short f2bf(float f) {
  union { float f; unsigned u; } x; x.f = f;
  unsigned r = x.u + 0x7FFFu + ((x.u >> 16) & 1u);
  return (unsigned short)(r >> 16);
}
__device__ __forceinline__ float bf2f(unsigned short b) {
  union { unsigned u; float f; } x; x.u = ((unsigned)b) << 16;
  return x.f;
}

__device__ __forceinline__ void gld_lds16(const void* g, void* l) {
  __builtin_amdgcn_global_load_lds(
      (const __attribute__((address_space(1))) unsigned int*)g,
      (__attribute__((address_space(3))) unsigned int*)l, 16, 0, 0);
}

// -------- fused fp32 -> bf16 bulk convert for x, qkv_w, proj_w --------------
__global__ __launch_bounds__(256) void cvt3_kernel(const float* __restrict__ s0,
                                                   unsigned short* __restrict__ d0, int n0,
                                                   const float* __restrict__ s1,
                                                   unsigned short* __restrict__ d1, int n1,
                                                   const float* __restrict__ s2,
                                                   unsigned short* __restrict__ d2, int n2) {
  int i = blockIdx.x * 256 + threadIdx.x;
  const int stride = gridDim.x * 256;
  const int tot = n0 + n1 + n2;
  for (; i < tot; i += stride) {
    const float* s;
    unsigned short* d;
    int j = i;
    if (j < n0) { s = s0; d = d0; }
    else if (j < n0 + n1) { j -= n0; s = s1; d = d1; }
    else { j -= n0 + n1; s = s2; d = d2; }
    float4 f0 = ((const float4*)s)[2 * j];
    float4 f1 = ((const float4*)s)[2 * j + 1];
    u16x8 v;
    v[0] = f2bf(f0.x); v[1] = f2bf(f0.y); v[2] = f2bf(f0.z); v[3] = f2bf(f0.w);
    v[4] = f2bf(f1.x); v[5] = f2bf(f1.y); v[6] = f2bf(f1.z); v[7] = f2bf(f1.w);
    ((u16x8*)d)[j] = v;
  }
}

// ---------------- GEMM1 (fused, proven R2 m97 structure) --------------------
// GEMM exploration CLOSED (0/5): R3/R4/R7/R11/R13 all lost to this 2-barrier
// structure at K=768 (163 us, ~550 TF).
__global__ __launch_bounds__(256) void qkv_gemm(const unsigned short* __restrict__ X,
                                                const unsigned short* __restrict__ W,
                                                unsigned short* __restrict__ Qo,
                                                unsigned short* __restrict__ Ko,
                                                unsigned short* __restrict__ Vo) {
  __shared__ unsigned short As[128][64];
  __shared__ unsigned short Bs[128][64];
  const int tid = threadIdx.x;
  const int lane = tid & 63, wave = tid >> 6;
  const int lrow = lane & 15, lgrp = lane >> 4;
  const int wr = wave >> 1, wc = wave & 1;
  const int m0 = blockIdx.x * 128, n0 = blockIdx.y * 128;

  f32x4 acc[4][4];
#pragma unroll
  for (int i = 0; i < 4; i++)
#pragma unroll
    for (int j = 0; j < 4; j++) acc[i][j] = (f32x4){0.f, 0.f, 0.f, 0.f};

  const int rbase = wave * 32;
  const int srow = rbase + (lane >> 3);
  const int scol = (lane & 7) * 8;

  for (int k0 = 0; k0 < 768; k0 += 64) {
    const unsigned short* ga = X + (size_t)(m0 + srow) * 768 + k0 + scol;
    const unsigned short* gb = W + (size_t)(n0 + srow) * 768 + k0 + scol;
#pragma unroll
    for (int i = 0; i < 4; i++) {
      gld_lds16(ga + (size_t)i * 8 * 768, &As[rbase + i * 8][0]);
      gld_lds16(gb + (size_t)i * 8 * 768, &Bs[rbase + i * 8][0]);
    }
    __syncthreads();
#pragma unroll
    for (int kk = 0; kk < 2; kk++) {
      bf16x8 a[4], b[4];
#pragma unroll
      for (int f = 0; f < 4; f++) {
        a[f] = *(const bf16x8*)(&As[wr * 64 + f * 16 + lrow][kk * 32 + lgrp * 8]);
        b[f] = *(const bf16x8*)(&Bs[wc * 64 + f * 16 + lrow][kk * 32 + lgrp * 8]);
      }
#pragma unroll
      for (int i = 0; i < 4; i++)
#pragma unroll
        for (int j = 0; j < 4; j++) acc[i][j] = MFMA16(a[i], b[j], acc[i][j]);
    }
    __syncthreads();
  }

#pragma unroll
  for (int fj = 0; fj < 4; fj++) {
    const int jb = n0 + wc * 64 + fj * 16;
    const int s = jb / 768;
    const int hh = (jb % 768) >> 6;
    const int dd = (jb & 63) + lrow;
    unsigned short* dst = (s == 0) ? Qo : (s == 1) ? Ko : Vo;
#pragma unroll
    for (int fi = 0; fi < 4; fi++) {
#pragma unroll
      for (int r = 0; r < 4; r++) {
        int m = m0 + wr * 64 + fi * 16 + lgrp * 4 + r;
        int bb = m / 197;
        int nn = m - bb * 197;
        dst[(size_t)((bb * 12 + hh) * 197 + nn) * 64 + dd] = f2bf(acc[fi][fj][r]);
      }
    }
  }
}

// ---------------- GEMM3 (proven R2 structure) -------------------------------
__global__ __launch_bounds__(256) void proj_gemm(const unsigned short* __restrict__ A,
                                                 const unsigned short* __restrict__ W,
                                                 const float* __restrict__ bias,
                                                 float* __restrict__ out) {
  __shared__ unsigned short As[128][64];
  __shared__ unsigned short Bs[128][64];
  const int tid = threadIdx.x;
  const int lane = tid & 63, wave = tid >> 6;
  const int lrow = lane & 15, lgrp = lane >> 4;
  const int wr = wave >> 1, wc = wave & 1;
  const int m0 = blockIdx.x * 128, n0 = blockIdx.y * 128;

  f32x4 acc[4][4];
#pragma unroll
  for (int i = 0; i < 4; i++)
#pragma unroll
    for (int j = 0; j < 4; j++) acc[i][j] = (f32x4){0.f, 0.f, 0.f, 0.f};

  const int rbase = wave * 32;
  const int srow = rbase + (lane >> 3);
  const int scol = (lane & 7) * 8;

  for (int k0 = 0; k0 < 768; k0 += 64) {
    const unsigned short* ga = A + (size_t)(m0 + srow) * 768 + k0 + scol;
    const unsigned short* gb = W + (size_t)(n0 + srow) * 768 + k0 + scol;
#pragma unroll
    for (int i = 0; i < 4; i++) {
      gld_lds16(ga + (size_t)i * 8 * 768, &As[rbase + i * 8][0]);
      gld_lds16(gb + (size_t)i * 8 * 768, &Bs[rbase + i * 8][0]);
    }
    __syncthreads();
#pragma unroll
    for (int kk = 0; kk < 2; kk++) {
      bf16x8 a[4], b[4];
#pragma unroll
      for (int f = 0; f < 4; f++) {
        a[f] = *(const bf16x8*)(&As[wr * 64 + f * 16 + lrow][kk * 32 + lgrp * 8]);
        b[f] = *(const bf16x8*)(&Bs[wc * 64 + f * 16 + lrow][kk * 32 + lgrp * 8]);
      }
#pragma unroll
      for (int i = 0; i < 4; i++)
#pragma unroll
        for (int j = 0; j < 4; j++) acc[i][j] = MFMA16(a[i], b[j], acc[i][j]);
    }
    __syncthreads();
  }

#pragma unroll
  for (int fj = 0; fj < 4; fj++) {
    const int j = n0 + wc * 64 + fj * 16 + lrow;
    const float bj = bias[j];
#pragma unroll
    for (int fi = 0; fi < 4; fi++) {
#pragma unroll
      for (int r = 0; r < 4; r++) {
        int m = m0 + wr * 64 + fi * 16 + lgrp * 4 + r;
        out[(size_t)m * 768 + j] = acc[fi][fj][r] + bj;
      }
    }
  }
}

// ===== Attention v6 (best: online PV, 2 blocks/CU, 3 barriers, exp2) ========
__global__ __launch_bounds__(512, 4) void attn_kernel(const unsigned short* __restrict__ Q,
                                                      const unsigned short* __restrict__ K,
                                                      const unsigned short* __restrict__ V,
                                                      const float* __restrict__ piq,
                                                      const float* __restrict__ pik,
                                                      unsigned short* __restrict__ Oa) {
  __shared__ __align__(16) unsigned char smem[81536];
  unsigned short* Ks = (unsigned short*)smem;               // [208][64] swz
  unsigned short* Vt = (unsigned short*)(smem + 26624);     // [64][216]
  unsigned short* Ps = (unsigned short*)(smem + 54272);     // [8][16][40]
  unsigned short* Vlin = (unsigned short*)(smem + 54272);   // [200][64] alias
  float* k2c = (float*)(smem + 79872);                      // [208]
  float* piqs = k2c + 208;                                  // [208]

  const int tid = threadIdx.x;
  const int lane = tid & 63, wave = tid >> 6;
  const int lrow = lane & 15, lgrp = lane >> 4;
  const int bh = blockIdx.x;
  const int h = bh % 12;
  const int b = bh / 12;
  const size_t kvbase = (size_t)bh * 197 * 64;
  const float c1 = -0.09016844005556021f;  // -0.0625 * log2(e)

  float my_pik = 0.f, my_piq = 0.f;
  if (tid < 197) { my_pik = pik[h * 197 + tid]; my_piq = piq[h * 197 + tid]; }
  const int t0 = wave, t1 = wave + 8;
  const int rq0 = min(t0 * 16 + lrow, 196);
  const int rq1 = (t1 < 13) ? min(t1 * 16 + lrow, 196) : rq0;
  const size_t qb0 = kvbase + (size_t)rq0 * 64 + lgrp * 8;
  const size_t qb1 = kvbase + (size_t)rq1 * 64 + lgrp * 8;
  const bf16x8 aqA0 = *(const bf16x8*)(Q + qb0);
  const bf16x8 aqA1 = *(const bf16x8*)(Q + qb0 + 32);
  const bf16x8 aqB0 = *(const bf16x8*)(Q + qb1);
  const bf16x8 aqB1 = *(const bf16x8*)(Q + qb1 + 32);

  {
    const int rl = lane >> 3;
    const int csw = ((lane & 7) ^ rl) * 8;
    const int cl = (lane & 7) * 8;
    for (int i = wave; i < 26; i += 8)
      gld_lds16(K + kvbase + (size_t)(i * 8 + rl) * 64 + csw, Ks + i * 512);
    for (int i = wave; i < 25; i += 8)
      gld_lds16(V + kvbase + (size_t)(i * 8 + rl) * 64 + cl, Vlin + i * 512);
  }
  __syncthreads();

  for (int c = tid; c < 1600; c += 512) {
    const int row = c >> 3, d0 = (c & 7) * 8;
    u16x8 v = *(const u16x8*)(Vlin + row * 64 + d0);
#pragma unroll
    for (int e = 0; e < 8; e++) Vt[(d0 + e) * 216 + row] = (unsigned short)v[e];
  }
  {
    const int i1 = tid + 512;
    Vt[(tid >> 4) * 216 + 200 + (tid & 15)] = 0;
    Vt[(i1 >> 4) * 216 + 200 + (i1 & 15)] = 0;
  }
  if (tid < 208) {
    const int n = tid;
    if (n < 197) {
      float k2 = 0.f;
#pragma unroll
      for (int c = 0; c < 8; c++) {
        u16x8 v = *(const u16x8*)(Ks + n * 64 + ((c ^ (n & 7)) << 3));
#pragma unroll
        for (int e = 0; e < 8; e++) { float f = bf2f((unsigned short)v[e]); k2 += f * f; }
      }
      const float pk = fminf(fabsf(my_pik), 1.f);
      k2c[n] = c1 * k2 + log2f(pk);
      piqs[n] = fminf(fabsf(my_piq), 1.f);
    } else {
      k2c[n] = -__builtin_inff();
      piqs[n] = 0.f;
    }
  }
  __syncthreads();

  unsigned short* Pw = Ps + wave * 640;  // [16][40]

#define ATTN_TILE(TT, AQ0, AQ1)                                               \
  {                                                                           \
    const int n0_ = (TT) * 16;                                                \
    float q2p = 0.f;                                                          \
    _Pragma("unroll") for (int e = 0; e < 8; e++) {                           \
      float f0 = bf2f((unsigned short)((u16x8)(AQ0))[e]); q2p += f0 * f0;     \
      float f1 = bf2f((unsigned short)((u16x8)(AQ1))[e]); q2p += f1 * f1;     \
    }                                                                         \
    q2p += __shfl_xor(q2p, 16);                                               \
    q2p += __shfl_xor(q2p, 32);                                               \
    float q2r[4];                                                             \
    _Pragma("unroll") for (int r = 0; r < 4; r++)                             \
        q2r[r] = __shfl(q2p, lgrp * 4 + r);                                   \
    float rs[4] = {0.f, 0.f, 0.f, 0.f};                                       \
    f32x4 o[4];                                                               \
    _Pragma("unroll") for (int dt = 0; dt < 4; dt++)                          \
        o[dt] = (f32x4){0.f, 0.f, 0.f, 0.f};                                  \
    for (int ks = 0; ks < 7; ks++) {                                          \
      _Pragma("unroll") for (int half = 0; half < 2; half++) {                \
        const int jt = ks * 2 + half;                                         \
        if (jt < 13) {                                                        \
          f32x4 sacc = (f32x4){0.f, 0.f, 0.f, 0.f};                           \
          const int rk = jt * 16 + lrow;                                      \
          bf16x8 bk0 = *(const bf16x8*)(Ks + rk * 64 +                        \
                                        (((0 + lgrp) ^ (rk & 7)) << 3));      \
          bf16x8 bk1 = *(const bf16x8*)(Ks + rk * 64 +                        \
                                        (((4 + lgrp) ^ (rk & 7)) << 3));      \
          __builtin_amdgcn_s_setprio(1);                                      \
          sacc = MFMA16((AQ0), bk0, sacc);                                    \
          sacc = MFMA16((AQ1), bk1, sacc);                                    \
          __builtin_amdgcn_s_setprio(0);                                      \
          const int j = jt * 16 + lrow;                                       \
          const float k2cj = k2c[j];                                          \
          _Pragma("unroll") for (int r = 0; r < 4; r++) {                     \
            float t1v = fmaf(-2.f, sacc[r], q2r[r]);                          \
            float p = exp2f(fmaf(c1, t1v, k2cj));                             \
            rs[r] += p;                                                       \
            Pw[(lgrp * 4 + r) * 40 + half * 16 + lrow] = f2bf(p);             \
          }                                                                   \
        } else {                                                              \
          _Pragma("unroll") for (int r = 0; r < 4; r++)                       \
              Pw[(lgrp * 4 + r) * 40 + 16 + lrow] = 0;                        \
        }                                                                     \
      }                                                                       \
      bf16x8 ap = *(const bf16x8*)(Pw + lrow * 40 + lgrp * 8);                \
      const int jcol = min(ks * 32 + lgrp * 8, 208);                          \
      __builtin_amdgcn_s_setprio(1);                                          \
      _Pragma("unroll") for (int dt = 0; dt < 4; dt++) {                      \
        bf16x8 bv = *(const bf16x8*)(Vt + (dt * 16 + lrow) * 216 + jcol);     \
        o[dt] = MFMA16(ap, bv, o[dt]);                                        \
      }                                                                       \
      __builtin_amdgcn_s_setprio(0);                                          \
    }                                                                         \
    _Pragma("unroll") for (int r = 0; r < 4; r++) {                           \
      float v = rs[r];                                                        \
      v += __shfl_xor(v, 1);                                                  \
      v += __shfl_xor(v, 2);                                                  \
      v += __shfl_xor(v, 4);                                                  \
      v += __shfl_xor(v, 8);                                                  \
      rs[r] = v;                                                              \
    }                                                                         \
    float scale[4];                                                           \
    _Pragma("unroll") for (int r = 0; r < 4; r++) {                           \
      float pq = piqs[n0_ + lgrp * 4 + r];                                    \
      scale[r] = pq / (pq * rs[r] + 1e-6f);                                   \
    }                                                                         \
    _Pragma("unroll") for (int r = 0; r < 4; r++) {                           \
      const int n = n0_ + lgrp * 4 + r;                                       \
      if (n < 197) {                                                          \
        const size_t ob = ((size_t)(b * 197 + n)) * 768 + h * 64;             \
        _Pragma("unroll") for (int dt = 0; dt < 4; dt++)                      \
            Oa[ob + dt * 16 + lrow] = f2bf(o[dt][r] * scale[r]);              \
      }                                                                       \
    }                                                                         \
  }

  ATTN_TILE(t0, aqA0, aqA1);
  if (t1 < 13) ATTN_TILE(t1, aqB0, aqB1);
#undef ATTN_TILE
}

extern "C" void kernel_launch(void* const* d_in, const int* in_sizes, int n_in,
                              void* d_out, int out_size, void* d_ws, size_t ws_size,
                              hipStream_t stream) {
  const float* x = (const float*)d_in[0];
  const float* qkv_w = (const float*)d_in[1];
  const float* proj_w = (const float*)d_in[2];
  const float* proj_b = (const float*)d_in[3];
  const float* pi_q = (const float*)d_in[4];
  const float* pi_k = (const float*)d_in[5];
  float* out = (float*)d_out;

  unsigned short* ws = (unsigned short*)d_ws;
  const size_t S = (size_t)1536 * 197 * 64;  // 19,365,888 elems per tensor
  unsigned short* Q = ws;
  unsigned short* K = ws + S;
  unsigned short* V = ws + 2 * S;
  unsigned short* Xb = ws + 3 * S;   // aliased: Oa reuses this region after qkv
  unsigned short* Oa = Xb;
  unsigned short* Wb = ws + 4 * S;                 // 2304*768 bf16
  unsigned short* Pb = Wb + (size_t)2304 * 768;    // 768*768 bf16

  dim3 blk(256, 1, 1);
  dim3 blk512(512, 1, 1);
  cvt3_kernel<<<dim3(2048, 1, 1), blk, 0, stream>>>(x, Xb, 2420736,
                                                    qkv_w, Wb, 221184,
                                                    proj_w, Pb, 73728);
  qkv_gemm<<<dim3(197, 18, 1), blk, 0, stream>>>(Xb, Wb, Q, K, V);
  attn_kernel<<<dim3(1536, 1, 1), blk512, 0, stream>>>(Q, K, V, pi_q, pi_k, Oa);
  proj_gemm<<<dim3(197, 6, 1), blk, 0, stream>>>(Oa, Pb, proj_b, out);
}

// Round 15
// 280.650 us; speedup vs baseline: 1.2875x; 1.0511x over previous
//
#include <hip/hip_runtime.h>

typedef __attribute__((ext_vector_type(8))) short bf16x8;
typedef __attribute__((ext_vector_type(8))) unsigned short u16x8;
typedef __attribute__((ext_vector_type(4))) float f32x4;

#define MFMA16(a, b, c) __builtin_amdgcn_mfma_f32_16x16x32_bf16((a), (b), (c), 0, 0, 0)

__device__ __forceinline__ unsigned short f2bf(float f) {
  union { float f; unsigned u; } x; x.f = f;
  unsigned r = x.u + 0x7FFFu + ((x.u >> 16) & 1u);
  return (unsigned short)(r >> 16);
}
__device__ __forceinline__ float bf2f(unsigned short b) {
  union { unsigned u; float f; } x; x.u = ((unsigned)b) << 16;
  return x.f;
}

__device__ __forceinline__ void gld_lds16(const void* g, void* l) {
  __builtin_amdgcn_global_load_lds(
      (const __attribute__((address_space(1))) unsigned int*)g,
      (__attribute__((address_space(3))) unsigned int*)l, 16, 0, 0);
}

// -------- fused fp32 -> bf16 bulk convert for x, qkv_w, proj_w --------------
__global__ __launch_bounds__(256) void cvt3_kernel(const float* __restrict__ s0,
                                                   unsigned short* __restrict__ d0, int n0,
                                                   const float* __restrict__ s1,
                                                   unsigned short* __restrict__ d1, int n1,
                                                   const float* __restrict__ s2,
                                                   unsigned short* __restrict__ d2, int n2) {
  int i = blockIdx.x * 256 + threadIdx.x;
  const int stride = gridDim.x * 256;
  const int tot = n0 + n1 + n2;
  for (; i < tot; i += stride) {
    const float* s;
    unsigned short* d;
    int j = i;
    if (j < n0) { s = s0; d = d0; }
    else if (j < n0 + n1) { j -= n0; s = s1; d = d1; }
    else { j -= n0 + n1; s = s2; d = d2; }
    float4 f0 = ((const float4*)s)[2 * j];
    float4 f1 = ((const float4*)s)[2 * j + 1];
    u16x8 v;
    v[0] = f2bf(f0.x); v[1] = f2bf(f0.y); v[2] = f2bf(f0.z); v[3] = f2bf(f0.w);
    v[4] = f2bf(f1.x); v[5] = f2bf(f1.y); v[6] = f2bf(f1.z); v[7] = f2bf(f1.w);
    ((u16x8*)d)[j] = v;
  }
}

// XCD-chunked bijective block remap (T1-class, m204 bijective formula).
// Each XCD gets a CONTIGUOUS run of new-ids ordered m-strip-major (nl/NB =
// m-tile): the NB n-siblings sharing an X-strip run consecutively on one XCD
// -> X strip L2-hits, W fully L2-resident per XCD. Pure index permutation:
// accumulation bit-identical.
__device__ __forceinline__ int xcd_remap(int lid, int q, int r) {
  // total = 8*q + r; xcd = lid&7 owns (q + (xcd<r)) ids, contiguous base.
  const int xcd = lid & 7, pos = lid >> 3;
  const int base = (xcd < r) ? xcd * (q + 1) : r * (q + 1) + (xcd - r) * q;
  return base + pos;
}

// ---------------- GEMM1 (fused, proven R2 m97 structure + XCD remap) --------
// GEMM SCHEDULE exploration CLOSED (0/5): R3/R4/R7/R11/R13 all lost to this
// 2-barrier structure at K=768. This round: locality-only change.
__global__ __launch_bounds__(256) void qkv_gemm(const unsigned short* __restrict__ X,
                                                const unsigned short* __restrict__ W,
                                                unsigned short* __restrict__ Qo,
                                                unsigned short* __restrict__ Ko,
                                                unsigned short* __restrict__ Vo) {
  __shared__ unsigned short As[128][64];
  __shared__ unsigned short Bs[128][64];
  const int tid = threadIdx.x;
  const int lane = tid & 63, wave = tid >> 6;
  const int lrow = lane & 15, lgrp = lane >> 4;
  const int wr = wave >> 1, wc = wave & 1;
  // grid = 3546 linear blocks; 3546 = 8*443 + 2. Decode m-strip-major.
  const int nl = xcd_remap(blockIdx.x, 443, 2);
  const int mb = nl / 18, nb = nl - mb * 18;
  const int m0 = mb * 128, n0 = nb * 128;

  f32x4 acc[4][4];
#pragma unroll
  for (int i = 0; i < 4; i++)
#pragma unroll
    for (int j = 0; j < 4; j++) acc[i][j] = (f32x4){0.f, 0.f, 0.f, 0.f};

  const int rbase = wave * 32;
  const int srow = rbase + (lane >> 3);
  const int scol = (lane & 7) * 8;

  for (int k0 = 0; k0 < 768; k0 += 64) {
    const unsigned short* ga = X + (size_t)(m0 + srow) * 768 + k0 + scol;
    const unsigned short* gb = W + (size_t)(n0 + srow) * 768 + k0 + scol;
#pragma unroll
    for (int i = 0; i < 4; i++) {
      gld_lds16(ga + (size_t)i * 8 * 768, &As[rbase + i * 8][0]);
      gld_lds16(gb + (size_t)i * 8 * 768, &Bs[rbase + i * 8][0]);
    }
    __syncthreads();
#pragma unroll
    for (int kk = 0; kk < 2; kk++) {
      bf16x8 a[4], b[4];
#pragma unroll
      for (int f = 0; f < 4; f++) {
        a[f] = *(const bf16x8*)(&As[wr * 64 + f * 16 + lrow][kk * 32 + lgrp * 8]);
        b[f] = *(const bf16x8*)(&Bs[wc * 64 + f * 16 + lrow][kk * 32 + lgrp * 8]);
      }
#pragma unroll
      for (int i = 0; i < 4; i++)
#pragma unroll
        for (int j = 0; j < 4; j++) acc[i][j] = MFMA16(a[i], b[j], acc[i][j]);
    }
    __syncthreads();
  }

#pragma unroll
  for (int fj = 0; fj < 4; fj++) {
    const int jb = n0 + wc * 64 + fj * 16;
    const int s = jb / 768;
    const int hh = (jb % 768) >> 6;
    const int dd = (jb & 63) + lrow;
    unsigned short* dst = (s == 0) ? Qo : (s == 1) ? Ko : Vo;
#pragma unroll
    for (int fi = 0; fi < 4; fi++) {
#pragma unroll
      for (int r = 0; r < 4; r++) {
        int m = m0 + wr * 64 + fi * 16 + lgrp * 4 + r;
        int bb = m / 197;
        int nn = m - bb * 197;
        dst[(size_t)((bb * 12 + hh) * 197 + nn) * 64 + dd] = f2bf(acc[fi][fj][r]);
      }
    }
  }
}

// ---------------- GEMM3 (proven R2 structure + XCD remap) -------------------
__global__ __launch_bounds__(256) void proj_gemm(const unsigned short* __restrict__ A,
                                                 const unsigned short* __restrict__ W,
                                                 const float* __restrict__ bias,
                                                 float* __restrict__ out) {
  __shared__ unsigned short As[128][64];
  __shared__ unsigned short Bs[128][64];
  const int tid = threadIdx.x;
  const int lane = tid & 63, wave = tid >> 6;
  const int lrow = lane & 15, lgrp = lane >> 4;
  const int wr = wave >> 1, wc = wave & 1;
  // grid = 1182 linear blocks; 1182 = 8*147 + 6. Decode m-strip-major.
  const int nl = xcd_remap(blockIdx.x, 147, 6);
  const int mb = nl / 6, nb = nl - mb * 6;
  const int m0 = mb * 128, n0 = nb * 128;

  f32x4 acc[4][4];
#pragma unroll
  for (int i = 0; i < 4; i++)
#pragma unroll
    for (int j = 0; j < 4; j++) acc[i][j] = (f32x4){0.f, 0.f, 0.f, 0.f};

  const int rbase = wave * 32;
  const int srow = rbase + (lane >> 3);
  const int scol = (lane & 7) * 8;

  for (int k0 = 0; k0 < 768; k0 += 64) {
    const unsigned short* ga = A + (size_t)(m0 + srow) * 768 + k0 + scol;
    const unsigned short* gb = W + (size_t)(n0 + srow) * 768 + k0 + scol;
#pragma unroll
    for (int i = 0; i < 4; i++) {
      gld_lds16(ga + (size_t)i * 8 * 768, &As[rbase + i * 8][0]);
      gld_lds16(gb + (size_t)i * 8 * 768, &Bs[rbase + i * 8][0]);
    }
    __syncthreads();
#pragma unroll
    for (int kk = 0; kk < 2; kk++) {
      bf16x8 a[4], b[4];
#pragma unroll
      for (int f = 0; f < 4; f++) {
        a[f] = *(const bf16x8*)(&As[wr * 64 + f * 16 + lrow][kk * 32 + lgrp * 8]);
        b[f] = *(const bf16x8*)(&Bs[wc * 64 + f * 16 + lrow][kk * 32 + lgrp * 8]);
      }
#pragma unroll
      for (int i = 0; i < 4; i++)
#pragma unroll
        for (int j = 0; j < 4; j++) acc[i][j] = MFMA16(a[i], b[j], acc[i][j]);
    }
    __syncthreads();
  }

#pragma unroll
  for (int fj = 0; fj < 4; fj++) {
    const int j = n0 + wc * 64 + fj * 16 + lrow;
    const float bj = bias[j];
#pragma unroll
    for (int fi = 0; fi < 4; fi++) {
#pragma unroll
      for (int r = 0; r < 4; r++) {
        int m = m0 + wr * 64 + fi * 16 + lgrp * 4 + r;
        out[(size_t)m * 768 + j] = acc[fi][fj][r] + bj;
      }
    }
  }
}

// ===== Attention v6 (frozen: online PV, 2 blocks/CU, 3 barriers, exp2) ======
__global__ __launch_bounds__(512, 4) void attn_kernel(const unsigned short* __restrict__ Q,
                                                      const unsigned short* __restrict__ K,
                                                      const unsigned short* __restrict__ V,
                                                      const float* __restrict__ piq,
                                                      const float* __restrict__ pik,
                                                      unsigned short* __restrict__ Oa) {
  __shared__ __align__(16) unsigned char smem[81536];
  unsigned short* Ks = (unsigned short*)smem;               // [208][64] swz
  unsigned short* Vt = (unsigned short*)(smem + 26624);     // [64][216]
  unsigned short* Ps = (unsigned short*)(smem + 54272);     // [8][16][40]
  unsigned short* Vlin = (unsigned short*)(smem + 54272);   // [200][64] alias
  float* k2c = (float*)(smem + 79872);                      // [208]
  float* piqs = k2c + 208;                                  // [208]

  const int tid = threadIdx.x;
  const int lane = tid & 63, wave = tid >> 6;
  const int lrow = lane & 15, lgrp = lane >> 4;
  const int bh = blockIdx.x;
  const int h = bh % 12;
  const int b = bh / 12;
  const size_t kvbase = (size_t)bh * 197 * 64;
  const float c1 = -0.09016844005556021f;  // -0.0625 * log2(e)

  float my_pik = 0.f, my_piq = 0.f;
  if (tid < 197) { my_pik = pik[h * 197 + tid]; my_piq = piq[h * 197 + tid]; }
  const int t0 = wave, t1 = wave + 8;
  const int rq0 = min(t0 * 16 + lrow, 196);
  const int rq1 = (t1 < 13) ? min(t1 * 16 + lrow, 196) : rq0;
  const size_t qb0 = kvbase + (size_t)rq0 * 64 + lgrp * 8;
  const size_t qb1 = kvbase + (size_t)rq1 * 64 + lgrp * 8;
  const bf16x8 aqA0 = *(const bf16x8*)(Q + qb0);
  const bf16x8 aqA1 = *(const bf16x8*)(Q + qb0 + 32);
  const bf16x8 aqB0 = *(const bf16x8*)(Q + qb1);
  const bf16x8 aqB1 = *(const bf16x8*)(Q + qb1 + 32);

  {
    const int rl = lane >> 3;
    const int csw = ((lane & 7) ^ rl) * 8;
    const int cl = (lane & 7) * 8;
    for (int i = wave; i < 26; i += 8)
      gld_lds16(K + kvbase + (size_t)(i * 8 + rl) * 64 + csw, Ks + i * 512);
    for (int i = wave; i < 25; i += 8)
      gld_lds16(V + kvbase + (size_t)(i * 8 + rl) * 64 + cl, Vlin + i * 512);
  }
  __syncthreads();

  for (int c = tid; c < 1600; c += 512) {
    const int row = c >> 3, d0 = (c & 7) * 8;
    u16x8 v = *(const u16x8*)(Vlin + row * 64 + d0);
#pragma unroll
    for (int e = 0; e < 8; e++) Vt[(d0 + e) * 216 + row] = (unsigned short)v[e];
  }
  {
    const int i1 = tid + 512;
    Vt[(tid >> 4) * 216 + 200 + (tid & 15)] = 0;
    Vt[(i1 >> 4) * 216 + 200 + (i1 & 15)] = 0;
  }
  if (tid < 208) {
    const int n = tid;
    if (n < 197) {
      float k2 = 0.f;
#pragma unroll
      for (int c = 0; c < 8; c++) {
        u16x8 v = *(const u16x8*)(Ks + n * 64 + ((c ^ (n & 7)) << 3));
#pragma unroll
        for (int e = 0; e < 8; e++) { float f = bf2f((unsigned short)v[e]); k2 += f * f; }
      }
      const float pk = fminf(fabsf(my_pik), 1.f);
      k2c[n] = c1 * k2 + log2f(pk);
      piqs[n] = fminf(fabsf(my_piq), 1.f);
    } else {
      k2c[n] = -__builtin_inff();
      piqs[n] = 0.f;
    }
  }
  __syncthreads();

  unsigned short* Pw = Ps + wave * 640;  // [16][40]

#define ATTN_TILE(TT, AQ0, AQ1)                                               \
  {                                                                           \
    const int n0_ = (TT) * 16;                                                \
    float q2p = 0.f;                                                          \
    _Pragma("unroll") for (int e = 0; e < 8; e++) {                           \
      float f0 = bf2f((unsigned short)((u16x8)(AQ0))[e]); q2p += f0 * f0;     \
      float f1 = bf2f((unsigned short)((u16x8)(AQ1))[e]); q2p += f1 * f1;     \
    }                                                                         \
    q2p += __shfl_xor(q2p, 16);                                               \
    q2p += __shfl_xor(q2p, 32);                                               \
    float q2r[4];                                                             \
    _Pragma("unroll") for (int r = 0; r < 4; r++)                             \
        q2r[r] = __shfl(q2p, lgrp * 4 + r);                                   \
    float rs[4] = {0.f, 0.f, 0.f, 0.f};                                       \
    f32x4 o[4];                                                               \
    _Pragma("unroll") for (int dt = 0; dt < 4; dt++)                          \
        o[dt] = (f32x4){0.f, 0.f, 0.f, 0.f};                                  \
    for (int ks = 0; ks < 7; ks++) {                                          \
      _Pragma("unroll") for (int half = 0; half < 2; half++) {                \
        const int jt = ks * 2 + half;                                         \
        if (jt < 13) {                                                        \
          f32x4 sacc = (f32x4){0.f, 0.f, 0.f, 0.f};                           \
          const int rk = jt * 16 + lrow;                                      \
          bf16x8 bk0 = *(const bf16x8*)(Ks + rk * 64 +                        \
                                        (((0 + lgrp) ^ (rk & 7)) << 3));      \
          bf16x8 bk1 = *(const bf16x8*)(Ks + rk * 64 +                        \
                                        (((4 + lgrp) ^ (rk & 7)) << 3));      \
          __builtin_amdgcn_s_setprio(1);                                      \
          sacc = MFMA16((AQ0), bk0, sacc);                                    \
          sacc = MFMA16((AQ1), bk1, sacc);                                    \
          __builtin_amdgcn_s_setprio(0);                                      \
          const int j = jt * 16 + lrow;                                       \
          const float k2cj = k2c[j];                                          \
          _Pragma("unroll") for (int r = 0; r < 4; r++) {                     \
            float t1v = fmaf(-2.f, sacc[r], q2r[r]);                          \
            float p = exp2f(fmaf(c1, t1v, k2cj));                             \
            rs[r] += p;                                                       \
            Pw[(lgrp * 4 + r) * 40 + half * 16 + lrow] = f2bf(p);             \
          }                                                                   \
        } else {                                                              \
          _Pragma("unroll") for (int r = 0; r < 4; r++)                       \
              Pw[(lgrp * 4 + r) * 40 + 16 + lrow] = 0;                        \
        }                                                                     \
      }                                                                       \
      bf16x8 ap = *(const bf16x8*)(Pw + lrow * 40 + lgrp * 8);                \
      const int jcol = min(ks * 32 + lgrp * 8, 208);                          \
      __builtin_amdgcn_s_setprio(1);                                          \
      _Pragma("unroll") for (int dt = 0; dt < 4; dt++) {                      \
        bf16x8 bv = *(const bf16x8*)(Vt + (dt * 16 + lrow) * 216 + jcol);     \
        o[dt] = MFMA16(ap, bv, o[dt]);                                        \
      }                                                                       \
      __builtin_amdgcn_s_setprio(0);                                          \
    }                                                                         \
    _Pragma("unroll") for (int r = 0; r < 4; r++) {                           \
      float v = rs[r];                                                        \
      v += __shfl_xor(v, 1);                                                  \
      v += __shfl_xor(v, 2);                                                  \
      v += __shfl_xor(v, 4);                                                  \
      v += __shfl_xor(v, 8);                                                  \
      rs[r] = v;                                                              \
    }                                                                         \
    float scale[4];                                                           \
    _Pragma("unroll") for (int r = 0; r < 4; r++) {                           \
      float pq = piqs[n0_ + lgrp * 4 + r];                                    \
      scale[r] = pq / (pq * rs[r] + 1e-6f);                                   \
    }                                                                         \
    _Pragma("unroll") for (int r = 0; r < 4; r++) {                           \
      const int n = n0_ + lgrp * 4 + r;                                       \
      if (n < 197) {                                                          \
        const size_t ob = ((size_t)(b * 197 + n)) * 768 + h * 64;             \
        _Pragma("unroll") for (int dt = 0; dt < 4; dt++)                      \
            Oa[ob + dt * 16 + lrow] = f2bf(o[dt][r] * scale[r]);              \
      }                                                                       \
    }                                                                         \
  }

  ATTN_TILE(t0, aqA0, aqA1);
  if (t1 < 13) ATTN_TILE(t1, aqB0, aqB1);
#undef ATTN_TILE
}

extern "C" void kernel_launch(void* const* d_in, const int* in_sizes, int n_in,
                              void* d_out, int out_size, void* d_ws, size_t ws_size,
                              hipStream_t stream) {
  const float* x = (const float*)d_in[0];
  const float* qkv_w = (const float*)d_in[1];
  const float* proj_w = (const float*)d_in[2];
  const float* proj_b = (const float*)d_in[3];
  const float* pi_q = (const float*)d_in[4];
  const float* pi_k = (const float*)d_in[5];
  float* out = (float*)d_out;

  unsigned short* ws = (unsigned short*)d_ws;
  const size_t S = (size_t)1536 * 197 * 64;  // 19,365,888 elems per tensor
  unsigned short* Q = ws;
  unsigned short* K = ws + S;
  unsigned short* V = ws + 2 * S;
  unsigned short* Xb = ws + 3 * S;   // aliased: Oa reuses this region after qkv
  unsigned short* Oa = Xb;
  unsigned short* Wb = ws + 4 * S;                 // 2304*768 bf16
  unsigned short* Pb = Wb + (size_t)2304 * 768;    // 768*768 bf16

  dim3 blk(256, 1, 1);
  dim3 blk512(512, 1, 1);
  cvt3_kernel<<<dim3(2048, 1, 1), blk, 0, stream>>>(x, Xb, 2420736,
                                                    qkv_w, Wb, 221184,
                                                    proj_w, Pb, 73728);
  qkv_gemm<<<dim3(3546, 1, 1), blk, 0, stream>>>(Xb, Wb, Q, K, V);
  attn_kernel<<<dim3(1536, 1, 1), blk512, 0, stream>>>(Q, K, V, pi_q, pi_k, Oa);
  proj_gemm<<<dim3(1182, 1, 1), blk, 0, stream>>>(Oa, Pb, proj_b, out);
}

// Round 16
// 246.679 us; speedup vs baseline: 1.4648x; 1.1377x over previous
//
#include <hip/hip_runtime.h>

typedef __attribute__((ext_vector_type(8))) short bf16x8;
typedef __attribute__((ext_vector_type(8))) unsigned short u16x8;
typedef __attribute__((ext_vector_type(4))) float f32x4;

#define MFMA16(a, b, c) __builtin_amdgcn_mfma_f32_16x16x32_bf16((a), (b), (c), 0, 0, 0)

__device__ __forceinline__ unsigned short f2bf(float f) {
  union { float f; unsigned u; } x; x.f = f;
  unsigned r = x.u + 0x7FFFu + ((x.u >> 16) & 1u);
  return (unsigned short)(r >> 16);
}
__device__ __forceinline__ float bf2f(unsigned short b) {
  union { unsigned u; float f; } x; x.u = ((unsigned)b) << 16;
  return x.f;
}

__device__ __forceinline__ void gld_lds16(const void* g, void* l) {
  __builtin_amdgcn_global_load_lds(
      (const __attribute__((address_space(1))) unsigned int*)g,
      (__attribute__((address_space(3))) unsigned int*)l, 16, 0, 0);
}

// -------- fused fp32 -> bf16 bulk convert for x, qkv_w, proj_w --------------
__global__ __launch_bounds__(256) void cvt3_kernel(const float* __restrict__ s0,
                                                   unsigned short* __restrict__ d0, int n0,
                                                   const float* __restrict__ s1,
                                                   unsigned short* __restrict__ d1, int n1,
                                                   const float* __restrict__ s2,
                                                   unsigned short* __restrict__ d2, int n2) {
  int i = blockIdx.x * 256 + threadIdx.x;
  const int stride = gridDim.x * 256;
  const int tot = n0 + n1 + n2;
  for (; i < tot; i += stride) {
    const float* s;
    unsigned short* d;
    int j = i;
    if (j < n0) { s = s0; d = d0; }
    else if (j < n0 + n1) { j -= n0; s = s1; d = d1; }
    else { j -= n0 + n1; s = s2; d = d2; }
    float4 f0 = ((const float4*)s)[2 * j];
    float4 f1 = ((const float4*)s)[2 * j + 1];
    u16x8 v;
    v[0] = f2bf(f0.x); v[1] = f2bf(f0.y); v[2] = f2bf(f0.z); v[3] = f2bf(f0.w);
    v[4] = f2bf(f1.x); v[5] = f2bf(f1.y); v[6] = f2bf(f1.z); v[7] = f2bf(f1.w);
    ((u16x8*)d)[j] = v;
  }
}

// XCD-chunked bijective block remap (proven +14 us in R15).
__device__ __forceinline__ int xcd_remap(int lid, int q, int r) {
  const int xcd = lid & 7, pos = lid >> 3;
  const int base = (xcd < r) ? xcd * (q + 1) : r * (q + 1) + (xcd - r) * q;
  return base + pos;
}

// ---------------- GEMM1 (R15 structure + T2 swizzle, NOTHING else) ----------
// Swizzle: LDS chunk c of row holds global chunk c^(row&7); staged via
// pre-swizzled GLOBAL source (gld_lds dest stays linear, rule #21); fragment
// ds_reads XOR the same key. 16-way -> 8-way(=b128 minimum) bank pattern.
// Operands and accumulation order bit-identical -> absmax 9.765625e-4.
__global__ __launch_bounds__(256) void qkv_gemm(const unsigned short* __restrict__ X,
                                                const unsigned short* __restrict__ W,
                                                unsigned short* __restrict__ Qo,
                                                unsigned short* __restrict__ Ko,
                                                unsigned short* __restrict__ Vo) {
  __shared__ unsigned short As[128][64];
  __shared__ unsigned short Bs[128][64];
  const int tid = threadIdx.x;
  const int lane = tid & 63, wave = tid >> 6;
  const int lrow = lane & 15, lgrp = lane >> 4;
  const int wr = wave >> 1, wc = wave & 1;
  const int nl = xcd_remap(blockIdx.x, 443, 2);   // 3546 = 8*443+2
  const int mb = nl / 18, nb = nl - mb * 18;
  const int m0 = mb * 128, n0 = nb * 128;

  f32x4 acc[4][4];
#pragma unroll
  for (int i = 0; i < 4; i++)
#pragma unroll
    for (int j = 0; j < 4; j++) acc[i][j] = (f32x4){0.f, 0.f, 0.f, 0.f};

  const int rbase = wave * 32;
  const int rl = lane >> 3;                  // 0..7 = staged row & 7
  const int srow = rbase + rl;
  const int gsw = ((lane & 7) ^ rl) * 8;     // pre-swizzled global chunk

  for (int k0 = 0; k0 < 768; k0 += 64) {
    const unsigned short* ga = X + (size_t)(m0 + srow) * 768 + k0 + gsw;
    const unsigned short* gb = W + (size_t)(n0 + srow) * 768 + k0 + gsw;
#pragma unroll
    for (int i = 0; i < 4; i++) {
      gld_lds16(ga + (size_t)i * 8 * 768, &As[rbase + i * 8][0]);
      gld_lds16(gb + (size_t)i * 8 * 768, &Bs[rbase + i * 8][0]);
    }
    __syncthreads();
#pragma unroll
    for (int kk = 0; kk < 2; kk++) {
      bf16x8 a[4], b[4];
#pragma unroll
      for (int f = 0; f < 4; f++) {
        const int ra = wr * 64 + f * 16 + lrow;
        const int rb = wc * 64 + f * 16 + lrow;
        a[f] = *(const bf16x8*)(&As[ra][(((kk * 4 + lgrp) ^ (ra & 7)) << 3)]);
        b[f] = *(const bf16x8*)(&Bs[rb][(((kk * 4 + lgrp) ^ (rb & 7)) << 3)]);
      }
#pragma unroll
      for (int i = 0; i < 4; i++)
#pragma unroll
        for (int j = 0; j < 4; j++) acc[i][j] = MFMA16(a[i], b[j], acc[i][j]);
    }
    __syncthreads();
  }

#pragma unroll
  for (int fj = 0; fj < 4; fj++) {
    const int jb = n0 + wc * 64 + fj * 16;
    const int s = jb / 768;
    const int hh = (jb % 768) >> 6;
    const int dd = (jb & 63) + lrow;
    unsigned short* dst = (s == 0) ? Qo : (s == 1) ? Ko : Vo;
#pragma unroll
    for (int fi = 0; fi < 4; fi++) {
#pragma unroll
      for (int r = 0; r < 4; r++) {
        int m = m0 + wr * 64 + fi * 16 + lgrp * 4 + r;
        int bb = m / 197;
        int nn = m - bb * 197;
        dst[(size_t)((bb * 12 + hh) * 197 + nn) * 64 + dd] = f2bf(acc[fi][fj][r]);
      }
    }
  }
}

// ---------------- GEMM3 (R15 structure + T2 swizzle) ------------------------
__global__ __launch_bounds__(256) void proj_gemm(const unsigned short* __restrict__ A,
                                                 const unsigned short* __restrict__ W,
                                                 const float* __restrict__ bias,
                                                 float* __restrict__ out) {
  __shared__ unsigned short As[128][64];
  __shared__ unsigned short Bs[128][64];
  const int tid = threadIdx.x;
  const int lane = tid & 63, wave = tid >> 6;
  const int lrow = lane & 15, lgrp = lane >> 4;
  const int wr = wave >> 1, wc = wave & 1;
  const int nl = xcd_remap(blockIdx.x, 147, 6);   // 1182 = 8*147+6
  const int mb = nl / 6, nb = nl - mb * 6;
  const int m0 = mb * 128, n0 = nb * 128;

  f32x4 acc[4][4];
#pragma unroll
  for (int i = 0; i < 4; i++)
#pragma unroll
    for (int j = 0; j < 4; j++) acc[i][j] = (f32x4){0.f, 0.f, 0.f, 0.f};

  const int rbase = wave * 32;
  const int rl = lane >> 3;
  const int srow = rbase + rl;
  const int gsw = ((lane & 7) ^ rl) * 8;

  for (int k0 = 0; k0 < 768; k0 += 64) {
    const unsigned short* ga = A + (size_t)(m0 + srow) * 768 + k0 + gsw;
    const unsigned short* gb = W + (size_t)(n0 + srow) * 768 + k0 + gsw;
#pragma unroll
    for (int i = 0; i < 4; i++) {
      gld_lds16(ga + (size_t)i * 8 * 768, &As[rbase + i * 8][0]);
      gld_lds16(gb + (size_t)i * 8 * 768, &Bs[rbase + i * 8][0]);
    }
    __syncthreads();
#pragma unroll
    for (int kk = 0; kk < 2; kk++) {
      bf16x8 a[4], b[4];
#pragma unroll
      for (int f = 0; f < 4; f++) {
        const int ra = wr * 64 + f * 16 + lrow;
        const int rb = wc * 64 + f * 16 + lrow;
        a[f] = *(const bf16x8*)(&As[ra][(((kk * 4 + lgrp) ^ (ra & 7)) << 3)]);
        b[f] = *(const bf16x8*)(&Bs[rb][(((kk * 4 + lgrp) ^ (rb & 7)) << 3)]);
      }
#pragma unroll
      for (int i = 0; i < 4; i++)
#pragma unroll
        for (int j = 0; j < 4; j++) acc[i][j] = MFMA16(a[i], b[j], acc[i][j]);
    }
    __syncthreads();
  }

#pragma unroll
  for (int fj = 0; fj < 4; fj++) {
    const int j = n0 + wc * 64 + fj * 16 + lrow;
    const float bj = bias[j];
#pragma unroll
    for (int fi = 0; fi < 4; fi++) {
#pragma unroll
      for (int r = 0; r < 4; r++) {
        int m = m0 + wr * 64 + fi * 16 + lgrp * 4 + r;
        out[(size_t)m * 768 + j] = acc[fi][fj][r] + bj;
      }
    }
  }
}

// ===== Attention v6 (frozen: online PV, 2 blocks/CU, 3 barriers, exp2) ======
__global__ __launch_bounds__(512, 4) void attn_kernel(const unsigned short* __restrict__ Q,
                                                      const unsigned short* __restrict__ K,
                                                      const unsigned short* __restrict__ V,
                                                      const float* __restrict__ piq,
                                                      const float* __restrict__ pik,
                                                      unsigned short* __restrict__ Oa) {
  __shared__ __align__(16) unsigned char smem[81536];
  unsigned short* Ks = (unsigned short*)smem;               // [208][64] swz
  unsigned short* Vt = (unsigned short*)(smem + 26624);     // [64][216]
  unsigned short* Ps = (unsigned short*)(smem + 54272);     // [8][16][40]
  unsigned short* Vlin = (unsigned short*)(smem + 54272);   // [200][64] alias
  float* k2c = (float*)(smem + 79872);                      // [208]
  float* piqs = k2c + 208;                                  // [208]

  const int tid = threadIdx.x;
  const int lane = tid & 63, wave = tid >> 6;
  const int lrow = lane & 15, lgrp = lane >> 4;
  const int bh = blockIdx.x;
  const int h = bh % 12;
  const int b = bh / 12;
  const size_t kvbase = (size_t)bh * 197 * 64;
  const float c1 = -0.09016844005556021f;  // -0.0625 * log2(e)

  float my_pik = 0.f, my_piq = 0.f;
  if (tid < 197) { my_pik = pik[h * 197 + tid]; my_piq = piq[h * 197 + tid]; }
  const int t0 = wave, t1 = wave + 8;
  const int rq0 = min(t0 * 16 + lrow, 196);
  const int rq1 = (t1 < 13) ? min(t1 * 16 + lrow, 196) : rq0;
  const size_t qb0 = kvbase + (size_t)rq0 * 64 + lgrp * 8;
  const size_t qb1 = kvbase + (size_t)rq1 * 64 + lgrp * 8;
  const bf16x8 aqA0 = *(const bf16x8*)(Q + qb0);
  const bf16x8 aqA1 = *(const bf16x8*)(Q + qb0 + 32);
  const bf16x8 aqB0 = *(const bf16x8*)(Q + qb1);
  const bf16x8 aqB1 = *(const bf16x8*)(Q + qb1 + 32);

  {
    const int rl = lane >> 3;
    const int csw = ((lane & 7) ^ rl) * 8;
    const int cl = (lane & 7) * 8;
    for (int i = wave; i < 26; i += 8)
      gld_lds16(K + kvbase + (size_t)(i * 8 + rl) * 64 + csw, Ks + i * 512);
    for (int i = wave; i < 25; i += 8)
      gld_lds16(V + kvbase + (size_t)(i * 8 + rl) * 64 + cl, Vlin + i * 512);
  }
  __syncthreads();

  for (int c = tid; c < 1600; c += 512) {
    const int row = c >> 3, d0 = (c & 7) * 8;
    u16x8 v = *(const u16x8*)(Vlin + row * 64 + d0);
#pragma unroll
    for (int e = 0; e < 8; e++) Vt[(d0 + e) * 216 + row] = (unsigned short)v[e];
  }
  {
    const int i1 = tid + 512;
    Vt[(tid >> 4) * 216 + 200 + (tid & 15)] = 0;
    Vt[(i1 >> 4) * 216 + 200 + (i1 & 15)] = 0;
  }
  if (tid < 208) {
    const int n = tid;
    if (n < 197) {
      float k2 = 0.f;
#pragma unroll
      for (int c = 0; c < 8; c++) {
        u16x8 v = *(const u16x8*)(Ks + n * 64 + ((c ^ (n & 7)) << 3));
#pragma unroll
        for (int e = 0; e < 8; e++) { float f = bf2f((unsigned short)v[e]); k2 += f * f; }
      }
      const float pk = fminf(fabsf(my_pik), 1.f);
      k2c[n] = c1 * k2 + log2f(pk);
      piqs[n] = fminf(fabsf(my_piq), 1.f);
    } else {
      k2c[n] = -__builtin_inff();
      piqs[n] = 0.f;
    }
  }
  __syncthreads();

  unsigned short* Pw = Ps + wave * 640;  // [16][40]

#define ATTN_TILE(TT, AQ0, AQ1)                                               \
  {                                                                           \
    const int n0_ = (TT) * 16;                                                \
    float q2p = 0.f;                                                          \
    _Pragma("unroll") for (int e = 0; e < 8; e++) {                           \
      float f0 = bf2f((unsigned short)((u16x8)(AQ0))[e]); q2p += f0 * f0;     \
      float f1 = bf2f((unsigned short)((u16x8)(AQ1))[e]); q2p += f1 * f1;     \
    }                                                                         \
    q2p += __shfl_xor(q2p, 16);                                               \
    q2p += __shfl_xor(q2p, 32);                                               \
    float q2r[4];                                                             \
    _Pragma("unroll") for (int r = 0; r < 4; r++)                             \
        q2r[r] = __shfl(q2p, lgrp * 4 + r);                                   \
    float rs[4] = {0.f, 0.f, 0.f, 0.f};                                       \
    f32x4 o[4];                                                               \
    _Pragma("unroll") for (int dt = 0; dt < 4; dt++)                          \
        o[dt] = (f32x4){0.f, 0.f, 0.f, 0.f};                                  \
    for (int ks = 0; ks < 7; ks++) {                                          \
      _Pragma("unroll") for (int half = 0; half < 2; half++) {                \
        const int jt = ks * 2 + half;                                         \
        if (jt < 13) {                                                        \
          f32x4 sacc = (f32x4){0.f, 0.f, 0.f, 0.f};                           \
          const int rk = jt * 16 + lrow;                                      \
          bf16x8 bk0 = *(const bf16x8*)(Ks + rk * 64 +                        \
                                        (((0 + lgrp) ^ (rk & 7)) << 3));      \
          bf16x8 bk1 = *(const bf16x8*)(Ks + rk * 64 +                        \
                                        (((4 + lgrp) ^ (rk & 7)) << 3));      \
          __builtin_amdgcn_s_setprio(1);                                      \
          sacc = MFMA16((AQ0), bk0, sacc);                                    \
          sacc = MFMA16((AQ1), bk1, sacc);                                    \
          __builtin_amdgcn_s_setprio(0);                                      \
          const int j = jt * 16 + lrow;                                       \
          const float k2cj = k2c[j];                                          \
          _Pragma("unroll") for (int r = 0; r < 4; r++) {                     \
            float t1v = fmaf(-2.f, sacc[r], q2r[r]);                          \
            float p = exp2f(fmaf(c1, t1v, k2cj));                             \
            rs[r] += p;                                                       \
            Pw[(lgrp * 4 + r) * 40 + half * 16 + lrow] = f2bf(p);             \
          }                                                                   \
        } else {                                                              \
          _Pragma("unroll") for (int r = 0; r < 4; r++)                       \
              Pw[(lgrp * 4 + r) * 40 + 16 + lrow] = 0;                        \
        }                                                                     \
      }                                                                       \
      bf16x8 ap = *(const bf16x8*)(Pw + lrow * 40 + lgrp * 8);                \
      const int jcol = min(ks * 32 + lgrp * 8, 208);                          \
      __builtin_amdgcn_s_setprio(1);                                          \
      _Pragma("unroll") for (int dt = 0; dt < 4; dt++) {                      \
        bf16x8 bv = *(const bf16x8*)(Vt + (dt * 16 + lrow) * 216 + jcol);     \
        o[dt] = MFMA16(ap, bv, o[dt]);                                        \
      }                                                                       \
      __builtin_amdgcn_s_setprio(0);                                          \
    }                                                                         \
    _Pragma("unroll") for (int r = 0; r < 4; r++) {                           \
      float v = rs[r];                                                        \
      v += __shfl_xor(v, 1);                                                  \
      v += __shfl_xor(v, 2);                                                  \
      v += __shfl_xor(v, 4);                                                  \
      v += __shfl_xor(v, 8);                                                  \
      rs[r] = v;                                                              \
    }                                                                         \
    float scale[4];                                                           \
    _Pragma("unroll") for (int r = 0; r < 4; r++) {                           \
      float pq = piqs[n0_ + lgrp * 4 + r];                                    \
      scale[r] = pq / (pq * rs[r] + 1e-6f);                                   \
    }                                                                         \
    _Pragma("unroll") for (int r = 0; r < 4; r++) {                           \
      const int n = n0_ + lgrp * 4 + r;                                       \
      if (n < 197) {                                                          \
        const size_t ob = ((size_t)(b * 197 + n)) * 768 + h * 64;             \
        _Pragma("unroll") for (int dt = 0; dt < 4; dt++)                      \
            Oa[ob + dt * 16 + lrow] = f2bf(o[dt][r] * scale[r]);              \
      }                                                                       \
    }                                                                         \
  }

  ATTN_TILE(t0, aqA0, aqA1);
  if (t1 < 13) ATTN_TILE(t1, aqB0, aqB1);
#undef ATTN_TILE
}

extern "C" void kernel_launch(void* const* d_in, const int* in_sizes, int n_in,
                              void* d_out, int out_size, void* d_ws, size_t ws_size,
                              hipStream_t stream) {
  const float* x = (const float*)d_in[0];
  const float* qkv_w = (const float*)d_in[1];
  const float* proj_w = (const float*)d_in[2];
  const float* proj_b = (const float*)d_in[3];
  const float* pi_q = (const float*)d_in[4];
  const float* pi_k = (const float*)d_in[5];
  float* out = (float*)d_out;

  unsigned short* ws = (unsigned short*)d_ws;
  const size_t S = (size_t)1536 * 197 * 64;  // 19,365,888 elems per tensor
  unsigned short* Q = ws;
  unsigned short* K = ws + S;
  unsigned short* V = ws + 2 * S;
  unsigned short* Xb = ws + 3 * S;   // aliased: Oa reuses this region after qkv
  unsigned short* Oa = Xb;
  unsigned short* Wb = ws + 4 * S;                 // 2304*768 bf16
  unsigned short* Pb = Wb + (size_t)2304 * 768;    // 768*768 bf16

  dim3 blk(256, 1, 1);
  dim3 blk512(512, 1, 1);
  cvt3_kernel<<<dim3(2048, 1, 1), blk, 0, stream>>>(x, Xb, 2420736,
                                                    qkv_w, Wb, 221184,
                                                    proj_w, Pb, 73728);
  qkv_gemm<<<dim3(3546, 1, 1), blk, 0, stream>>>(Xb, Wb, Q, K, V);
  attn_kernel<<<dim3(1536, 1, 1), blk512, 0, stream>>>(Q, K, V, pi_q, pi_k, Oa);
  proj_gemm<<<dim3(1182, 1, 1), blk, 0, stream>>>(Oa, Pb, proj_b, out);
}